// Round 8
// baseline (1345.993 us; speedup 1.0000x reference)
//
#include <hip/hip_runtime.h>

#define TT 512
#define BB 64
#define EE 300
#define HH 150
#define G3 450
#define AT 75

typedef float v2f __attribute__((ext_vector_type(2)));

__device__ __forceinline__ float fast_rcp(float x) { return __builtin_amdgcn_rcpf(x); }
__device__ __forceinline__ float sigmoid_f(float x) { return fast_rcp(1.f + __expf(-x)); }
__device__ __forceinline__ float tanh_f(float x) {
  float e = __expf(2.f * x);
  return 1.f - 2.f * fast_rcp(e + 1.f);
}

// ---------------- weight prep ----------------
// Wih0T: [300][450] (k-major, coalesced across g). Wih1Tp: [152][450] zero-padded
// k=150..151. W1T, fc1T as before. Whh is consumed natively by k_pack.
__global__ void k_prep(const float* __restrict__ Wih0, const float* __restrict__ Wih1,
                       const float* __restrict__ W1,   const float* __restrict__ fc1w,
                       float* __restrict__ Wih0T, float* __restrict__ Wih1Tp,
                       float* __restrict__ W1T,   float* __restrict__ fc1T) {
  int tid = blockIdx.x * blockDim.x + threadIdx.x;
  int nt = gridDim.x * blockDim.x;
  for (int i = tid; i < G3 * EE; i += nt) { int r = i / EE, c = i - r * EE; Wih0T[c * G3 + r] = Wih0[i]; }
  for (int i = tid; i < 152 * G3; i += nt) {
    int k = i / G3, g = i - k * G3;
    Wih1Tp[i] = (k < HH) ? Wih1[g * HH + k] : 0.f;
  }
  for (int i = tid; i < AT * HH; i += nt) { int r = i / HH, c = i - r * HH; W1T[c * AT + r] = W1[i]; }
  for (int i = tid; i < HH * HH; i += nt) { int r = i / HH, c = i - r * HH; fc1T[c * HH + r] = fc1w[i]; }
}

// Pack Whh [450][150] into per-thread blocks for k_rec:
// thread tid=(s<<8)|p owns rows {2p,2p+1}, k-window [74s, 74s+76) (zero at the
// one pad k per slice). Layout: Wpk[tid*152 + q*4 + {r0k0,r0k1,r1k0,r1k1}].
__global__ void k_pack(const float* __restrict__ Whh, float* __restrict__ Wpk) {
  int f = blockIdx.x * 256 + threadIdx.x;
  if (f >= 512 * 152) return;
  int tid = f / 152, o = f - tid * 152;
  int s = tid >> 8, p = tid & 255;
  int q = o >> 2, c = o & 3, r = c >> 1, half = c & 1;
  int row = 2 * p + r, k = 74 * s + 2 * q + half;
  float v = 0.f;
  if (p < 225) {
    bool dead = (s == 0 && k >= 75) || (s == 1 && k < 75);
    if (!dead) v = Whh[row * HH + k];
  }
  Wpk[f] = v;
}

// ---------------- layer-0 input projection: gather + [32768,300]@[300,450] ----------------
// 128 threads, 4 g-columns/thread: broadcast LDS reads per block drop 8x vs
// the 512-thread/1-col version (the old kernel was LDS-pipe-bound).
__global__ __launch_bounds__(128, 2) void k_xw0(const int* __restrict__ texts,
                                                const float* __restrict__ emb,
                                                const float* __restrict__ WihT,
                                                const float* __restrict__ bih,
                                                float* __restrict__ xw) {
  __shared__ __align__(16) float a_lds[32 * EE];
  const int row0 = blockIdx.x * 32;
  const int tid = threadIdx.x;
  for (int p = tid; p < 32 * EE; p += 128) {
    int r = p / EE, e = p - r * EE;
    a_lds[p] = emb[(size_t)texts[row0 + r] * EE + e];
  }
  __syncthreads();
  const int g0 = tid, g1 = tid + 128, g2 = tid + 256;
  const bool has3 = (tid + 384) < G3;
  const int g3 = has3 ? tid + 384 : 0;
  float acc0[32], acc1[32], acc2[32], acc3[32];
#pragma unroll
  for (int r = 0; r < 32; ++r) { acc0[r] = 0.f; acc1[r] = 0.f; acc2[r] = 0.f; acc3[r] = 0.f; }
  const float4* a4 = reinterpret_cast<const float4*>(a_lds);
  for (int k = 0; k < EE; k += 4) {
    float wA[4], wB[4], wC[4], wD[4];
#pragma unroll
    for (int i = 0; i < 4; ++i) {
      const float* wr = WihT + (size_t)(k + i) * G3;
      wA[i] = wr[g0]; wB[i] = wr[g1]; wC[i] = wr[g2]; wD[i] = wr[g3];
    }
#pragma unroll
    for (int r = 0; r < 32; ++r) {
      const float4 av = a4[r * 75 + (k >> 2)];
      acc0[r] = fmaf(av.x, wA[0], acc0[r]); acc0[r] = fmaf(av.y, wA[1], acc0[r]);
      acc0[r] = fmaf(av.z, wA[2], acc0[r]); acc0[r] = fmaf(av.w, wA[3], acc0[r]);
      acc1[r] = fmaf(av.x, wB[0], acc1[r]); acc1[r] = fmaf(av.y, wB[1], acc1[r]);
      acc1[r] = fmaf(av.z, wB[2], acc1[r]); acc1[r] = fmaf(av.w, wB[3], acc1[r]);
      acc2[r] = fmaf(av.x, wC[0], acc2[r]); acc2[r] = fmaf(av.y, wC[1], acc2[r]);
      acc2[r] = fmaf(av.z, wC[2], acc2[r]); acc2[r] = fmaf(av.w, wC[3], acc2[r]);
      acc3[r] = fmaf(av.x, wD[0], acc3[r]); acc3[r] = fmaf(av.y, wD[1], acc3[r]);
      acc3[r] = fmaf(av.z, wD[2], acc3[r]); acc3[r] = fmaf(av.w, wD[3], acc3[r]);
    }
  }
  const float b0 = bih[g0], b1 = bih[g1], b2 = bih[g2], b3 = bih[g3];
#pragma unroll
  for (int r = 0; r < 32; ++r) {
    float* o = xw + (size_t)(row0 + r) * G3;
    o[g0] = acc0[r] + b0; o[g1] = acc1[r] + b1; o[g2] = acc2[r] + b2;
    if (has3) o[g3] = acc3[r] + b3;
  }
}

// ---------------- layer-1 input projection: [32768,150]@[150,450] ----------------
__global__ __launch_bounds__(128, 2) void k_xw1(const float* __restrict__ in,
                                                const float* __restrict__ WihTp,
                                                const float* __restrict__ bih,
                                                float* __restrict__ xw) {
  __shared__ __align__(16) float a_lds[32 * 152];
  const int row0 = blockIdx.x * 32;
  const int tid = threadIdx.x;
  for (int p = tid; p < 32 * 152; p += 128) {
    int r = p / 152, e = p - r * 152;
    a_lds[p] = (e < HH) ? in[(size_t)(row0 + r) * HH + e] : 0.f;
  }
  __syncthreads();
  const int g0 = tid, g1 = tid + 128, g2 = tid + 256;
  const bool has3 = (tid + 384) < G3;
  const int g3 = has3 ? tid + 384 : 0;
  float acc0[32], acc1[32], acc2[32], acc3[32];
#pragma unroll
  for (int r = 0; r < 32; ++r) { acc0[r] = 0.f; acc1[r] = 0.f; acc2[r] = 0.f; acc3[r] = 0.f; }
  const float4* a4 = reinterpret_cast<const float4*>(a_lds);
  for (int k = 0; k < 152; k += 4) {
    float wA[4], wB[4], wC[4], wD[4];
#pragma unroll
    for (int i = 0; i < 4; ++i) {
      const float* wr = WihTp + (size_t)(k + i) * G3;
      wA[i] = wr[g0]; wB[i] = wr[g1]; wC[i] = wr[g2]; wD[i] = wr[g3];
    }
#pragma unroll
    for (int r = 0; r < 32; ++r) {
      const float4 av = a4[r * 38 + (k >> 2)];
      acc0[r] = fmaf(av.x, wA[0], acc0[r]); acc0[r] = fmaf(av.y, wA[1], acc0[r]);
      acc0[r] = fmaf(av.z, wA[2], acc0[r]); acc0[r] = fmaf(av.w, wA[3], acc0[r]);
      acc1[r] = fmaf(av.x, wB[0], acc1[r]); acc1[r] = fmaf(av.y, wB[1], acc1[r]);
      acc1[r] = fmaf(av.z, wB[2], acc1[r]); acc1[r] = fmaf(av.w, wB[3], acc1[r]);
      acc2[r] = fmaf(av.x, wC[0], acc2[r]); acc2[r] = fmaf(av.y, wC[1], acc2[r]);
      acc2[r] = fmaf(av.z, wC[2], acc2[r]); acc2[r] = fmaf(av.w, wC[3], acc2[r]);
      acc3[r] = fmaf(av.x, wD[0], acc3[r]); acc3[r] = fmaf(av.y, wD[1], acc3[r]);
      acc3[r] = fmaf(av.z, wD[2], acc3[r]); acc3[r] = fmaf(av.w, wD[3], acc3[r]);
    }
  }
  const float b0 = bih[g0], b1 = bih[g1], b2 = bih[g2], b3 = bih[g3];
#pragma unroll
  for (int r = 0; r < 32; ++r) {
    float* o = xw + (size_t)(row0 + r) * G3;
    o[g0] = acc0[r] + b0; o[g1] = acc1[r] + b1; o[g2] = acc2[r] + b2;
    if (has3) o[g3] = acc3[r] + b3;
  }
}

// ---------------- GRU recurrence: one block (512 thr) per batch element ----------------
// Config F: thread (s=tid>>8, p=tid&255) owns rows {2p,2p+1} over k-window
// [74s, 74s+76). No wave spans slices. h is uniformized via v_readlane ->
// SGPR pairs; matvec is explicit v_pk_fma_f32 with the "s" scalar operand --
// moves the broadcast OFF the LDS pipe (rounds 4-7 were LDS-bound at ~160
// broadcast instrs/step; this is ~20).
__global__ __launch_bounds__(512, 2) void k_rec(const float* __restrict__ Wpk,
                                                const float* __restrict__ bhh,
                                                const float* __restrict__ xw,
                                                const int* __restrict__ lengths,
                                                float* __restrict__ out) {
  const int b = blockIdx.x;
  const int tid = threadIdx.x;
  const int lane = tid & 63;
  __shared__ float h_lds[160];     // 150 used + zero pad (v1 reads up to 153)
  __shared__ float part[452];
  __shared__ float hg[452];
  const int len = lengths[b];

  const int s = tid >> 8;
  const int p = tid & 255;
  const bool act = p < 225;
  const int base = s * 74;

  v2f w0[38], w1[38];
  {
    const float4* wp = reinterpret_cast<const float4*>(Wpk + (size_t)tid * 152);
#pragma unroll
    for (int q = 0; q < 38; ++q) {
      const float4 f = wp[q];
      w0[q][0] = f.x; w0[q][1] = f.y;
      w1[q][0] = f.z; w1[q][1] = f.w;
    }
  }
  float2 bb = {0.f, 0.f};
  if (act) bb = *reinterpret_cast<const float2*>(bhh + 2 * p);

  for (int i = tid; i < 160; i += 512) h_lds[i] = 0.f;
  float h_reg = 0.f;
  __syncthreads();

  const float* xwb = xw + (size_t)b * TT * G3;
  float* outb = out + (size_t)b * TT * HH;

  for (int t = 0; t < len; ++t) {
    // keep weights register-resident (prevent remat-from-load)
#pragma unroll
    for (int q = 0; q < 38; ++q) asm volatile("" : "+v"(w0[q]), "+v"(w1[q]));
    // prefetch xw[t] for the update phase
    float xr = 0.f, xz = 0.f, xn = 0.f;
    if (tid < HH) {
      const float* xwt = xwb + (size_t)t * G3;
      xr = xwt[tid]; xz = xwt[tid + HH]; xn = xwt[tid + 2 * HH];
    }
    // wave-distributed h window; uniformize via readlane
    const int i0 = __float_as_int(h_lds[base + lane]);
    const int i1 = __float_as_int(h_lds[base + 64 + (lane & 15)]);
    v2f a0 = {0.f, 0.f}, a1 = {0.f, 0.f};
#pragma unroll
    for (int q = 0; q < 38; ++q) {
      int lo, hi;
      if (2 * q < 64) {
        lo = __builtin_amdgcn_readlane(i0, 2 * q);
        hi = __builtin_amdgcn_readlane(i0, 2 * q + 1);
      } else {
        lo = __builtin_amdgcn_readlane(i1, 2 * q - 64);
        hi = __builtin_amdgcn_readlane(i1, 2 * q - 63);
      }
      const unsigned long long hp =
          (unsigned long long)(unsigned)lo | ((unsigned long long)(unsigned)hi << 32);
      asm("v_pk_fma_f32 %0, %1, %2, %0" : "+v"(a0) : "v"(w0[q]), "s"(hp));
      asm("v_pk_fma_f32 %0, %1, %2, %0" : "+v"(a1) : "v"(w1[q]), "s"(hp));
    }
    const float pr0 = a0[0] + a0[1];
    const float pr1 = a1[0] + a1[1];
    if (s == 1 && act) *reinterpret_cast<float2*>(&part[2 * p]) = make_float2(pr0, pr1);
    __syncthreads();
    if (s == 0 && act) {
      const float2 pp = *reinterpret_cast<const float2*>(&part[2 * p]);
      *reinterpret_cast<float2*>(&hg[2 * p]) =
          make_float2(pr0 + pp.x + bb.x, pr1 + pp.y + bb.y);
    }
    __syncthreads();
    if (tid < HH) {
      const float r = sigmoid_f(xr + hg[tid]);
      const float z = sigmoid_f(xz + hg[tid + HH]);
      const float n = tanh_f(xn + r * hg[tid + 2 * HH]);
      const float hnew = (1.f - z) * n + z * h_reg;
      h_reg = hnew;
      h_lds[tid] = hnew;
      outb[(size_t)t * HH + tid] = hnew;
    }
    __syncthreads();
  }
  const int rem = (TT - len) * HH;
  float* outp = outb + (size_t)len * HH;
  for (int i = tid; i < rem; i += 512) outp[i] = 0.f;
}

// ---------------- attention scores: tanh(out1 @ W1^T) @ w2^T ----------------
__global__ __launch_bounds__(256) void k_scores(const float* __restrict__ out1,
                                                const float* __restrict__ W1T,
                                                const float* __restrict__ w2,
                                                float* __restrict__ scores) {
  const int row0 = blockIdx.x * 32;
  const int tid = threadIdx.x;
  __shared__ float sc[32];
  if (tid < 32) sc[tid] = 0.f;
  __syncthreads();
  for (int p = tid; p < 32 * AT; p += 256) {
    const int r = p / AT, a = p - r * AT;
    const float* x = out1 + (size_t)(row0 + r) * HH;
    float a0 = 0.f, a1 = 0.f;
    for (int k = 0; k < HH; k += 2) {
      a0 = fmaf(W1T[k * AT + a], x[k], a0);
      a1 = fmaf(W1T[(k + 1) * AT + a], x[k + 1], a1);
    }
    atomicAdd(&sc[r], tanh_f(a0 + a1) * w2[a]);
  }
  __syncthreads();
  if (tid < 32) scores[row0 + tid] = sc[tid];
}

// ---------------- softmax + context + classifier head (per batch) ----------------
__global__ __launch_bounds__(512) void k_final(const float* __restrict__ out1,
                                               const float* __restrict__ scores,
                                               const float* __restrict__ fc1T,
                                               const float* __restrict__ fc1b,
                                               const float* __restrict__ fc2w,
                                               const float* __restrict__ fc2b,
                                               float* __restrict__ logits) {
  const int b = blockIdx.x;
  const int tid = threadIdx.x;
  __shared__ float attn[TT];
  __shared__ float red[16];
  __shared__ float ctx[152];
  __shared__ float h1[152];

  float sv = scores[b * TT + tid];
  float m = sv;
#pragma unroll
  for (int off = 32; off > 0; off >>= 1) m = fmaxf(m, __shfl_xor(m, off));
  const int wave = tid >> 6;
  if ((tid & 63) == 0) red[wave] = m;
  __syncthreads();
  if (tid == 0) {
    float mm = red[0];
#pragma unroll
    for (int i = 1; i < 8; ++i) mm = fmaxf(mm, red[i]);
    red[8] = mm;
  }
  __syncthreads();
  const float e = __expf(sv - red[8]);
  attn[tid] = e;
  float zz = e;
#pragma unroll
  for (int off = 32; off > 0; off >>= 1) zz += __shfl_xor(zz, off);
  if ((tid & 63) == 0) red[wave] = zz;
  __syncthreads();
  if (tid == 0) {
    float ss = 0.f;
#pragma unroll
    for (int i = 0; i < 8; ++i) ss += red[i];
    red[9] = ss;
  }
  __syncthreads();
  const float invZ = 1.f / red[9];

  if (tid < HH) {
    const float* o1b = out1 + (size_t)b * TT * HH;
    float c0 = 0.f, c1 = 0.f, c2 = 0.f, c3 = 0.f;
    for (int t = 0; t < TT; t += 4) {
      c0 = fmaf(attn[t + 0], o1b[(t + 0) * HH + tid], c0);
      c1 = fmaf(attn[t + 1], o1b[(t + 1) * HH + tid], c1);
      c2 = fmaf(attn[t + 2], o1b[(t + 2) * HH + tid], c2);
      c3 = fmaf(attn[t + 3], o1b[(t + 3) * HH + tid], c3);
    }
    ctx[tid] = ((c0 + c1) + (c2 + c3)) * invZ;
  }
  __syncthreads();
  if (tid < HH) {
    float d0 = 0.f, d1 = 0.f;
    for (int k = 0; k < HH; k += 2) {
      d0 = fmaf(fc1T[k * HH + tid], ctx[k], d0);
      d1 = fmaf(fc1T[(k + 1) * HH + tid], ctx[k + 1], d1);
    }
    h1[tid] = fmaxf(d0 + d1 + fc1b[tid], 0.f);
  }
  __syncthreads();
  if (tid == 0) {
    float acc = fc2b[0];
    for (int k = 0; k < HH; ++k) acc = fmaf(fc2w[k], h1[k], acc);
    logits[b] = acc;
  }
}

extern "C" void kernel_launch(void* const* d_in, const int* in_sizes, int n_in,
                              void* d_out, int out_size, void* d_ws, size_t ws_size,
                              hipStream_t stream) {
  const int* texts     = (const int*)d_in[0];
  const int* lengths   = (const int*)d_in[1];
  const float* emb     = (const float*)d_in[2];
  const float* Wih0    = (const float*)d_in[3];
  const float* Whh0    = (const float*)d_in[4];
  const float* bih0    = (const float*)d_in[5];
  const float* bhh0    = (const float*)d_in[6];
  const float* Wih1    = (const float*)d_in[7];
  const float* Whh1    = (const float*)d_in[8];
  const float* bih1    = (const float*)d_in[9];
  const float* bhh1    = (const float*)d_in[10];
  const float* W1      = (const float*)d_in[11];
  const float* w2      = (const float*)d_in[12];
  const float* fc1w    = (const float*)d_in[13];
  const float* fc1b    = (const float*)d_in[14];
  const float* fc2w    = (const float*)d_in[15];
  const float* fc2b    = (const float*)d_in[16];
  float* logits = (float*)d_out;

  float* ws = (float*)d_ws;
  size_t off = 0;
  auto alloc = [&](size_t n) { float* p = ws + off; off += (n + 3) & ~(size_t)3; return p; };
  float* Wih0T  = alloc((size_t)G3 * EE);
  float* Wih1Tp = alloc((size_t)G3 * 152);
  float* W1T    = alloc((size_t)AT * HH);
  float* fc1T   = alloc((size_t)HH * HH);
  float* Wpk0   = alloc((size_t)512 * 152);
  float* Wpk1   = alloc((size_t)512 * 152);
  float* xwbuf  = alloc((size_t)BB * TT * G3);   // reused for xw0 then xw1
  float* out0   = alloc((size_t)BB * TT * HH);
  float* out1   = alloc((size_t)BB * TT * HH);
  float* scores = alloc((size_t)BB * TT);
  (void)ws_size; (void)in_sizes; (void)n_in; (void)out_size;

  hipLaunchKernelGGL(k_prep, dim3(256), dim3(256), 0, stream,
                     Wih0, Wih1, W1, fc1w, Wih0T, Wih1Tp, W1T, fc1T);
  hipLaunchKernelGGL(k_pack, dim3(304), dim3(256), 0, stream, Whh0, Wpk0);
  hipLaunchKernelGGL(k_pack, dim3(304), dim3(256), 0, stream, Whh1, Wpk1);
  hipLaunchKernelGGL(k_xw0, dim3((BB * TT) / 32), dim3(128), 0, stream, texts, emb, Wih0T, bih0, xwbuf);
  hipLaunchKernelGGL(k_rec, dim3(BB), dim3(512), 0, stream, Wpk0, bhh0, xwbuf, lengths, out0);
  hipLaunchKernelGGL(k_xw1, dim3((BB * TT) / 32), dim3(128), 0, stream, out0, Wih1Tp, bih1, xwbuf);
  hipLaunchKernelGGL(k_rec, dim3(BB), dim3(512), 0, stream, Wpk1, bhh1, xwbuf, lengths, out1);
  hipLaunchKernelGGL(k_scores, dim3((BB * TT) / 32), dim3(256), 0, stream, out1, W1T, w2, scores);
  hipLaunchKernelGGL(k_final, dim3(BB), dim3(512), 0, stream, out1, scores, fc1T, fc1b, fc2w, fc2b, logits);
}